// Round 8
// baseline (749.596 us; speedup 1.0000x reference)
//
#include <hip/hip_runtime.h>
#include <hip/hip_bf16.h>
#include <stdint.h>
#include <stddef.h>

// ---------------------------------------------------------------------------
// BasicMambaBlock on MI355X (gfx950).
// R2: chunked scan (h_end = P*h0 + q per chunk).
// R5: scan_p3 thread-per-(b,d,chunk), states in regs; NC=64.   [verified R7]
// R8: split-K for the grid-starved GEMMs (N<=1024 -> 256/32 blocks = 1 blk/CU,
//     occupancy 10%, MfmaUtil 15%): blockIdx.z K-chunks write fp32 partials
//     (plain stores into dead pbuf region), small reduce kernels apply
//     bias/residual. ff2 SK=4, w_out SK=2, dbc SK=8.
// ---------------------------------------------------------------------------

typedef __bf16 bf16;
typedef __bf16 bf16x8 __attribute__((ext_vector_type(8)));
typedef float  f32x4  __attribute__((ext_vector_type(4)));

static constexpr int kB  = 2;
static constexpr int kL  = 2048;
static constexpr int kDM = 1024;          // d_model
static constexpr int kDI = 2048;          // d_inner
static constexpr int kM  = kB * kL;       // 4096 rows (B*L)
static constexpr int kNC = 64;            // scan chunks
static constexpr int kCH = kL / kNC;      // 32 steps per chunk

// ---------------- helpers ----------------
__device__ __forceinline__ void gload16(const void* g, void* l) {
  __builtin_amdgcn_global_load_lds((__attribute__((address_space(1))) void*)g,
                                   (__attribute__((address_space(3))) void*)l,
                                   16, 0, 0);
}

// ---------------- weight transpose fp32[K][N] -> bf16[Npad][K] --------------
__global__ __launch_bounds__(256) void transpose_to_bf16(
    const float* __restrict__ w, bf16* __restrict__ wt, int K, int N, int Npad) {
  __shared__ float t[32][33];
  const int k0 = blockIdx.x * 32, n0 = blockIdx.y * 32;
  const int tx = threadIdx.x & 31, ty = threadIdx.x >> 5;  // 32 x 8
#pragma unroll
  for (int i = ty; i < 32; i += 8) {
    float v = 0.f;
    if (k0 + i < K && n0 + tx < N) v = w[(size_t)(k0 + i) * N + n0 + tx];
    t[i][tx] = v;
  }
  __syncthreads();
#pragma unroll
  for (int i = ty; i < 32; i += 8) {
    const int n = n0 + i, k = k0 + tx;
    if (n < Npad && k < K) wt[(size_t)n * K + k] = (bf16)t[tx][i];
  }
}

// ---------------- layernorm (D=1024) -> bf16 ----------------
__global__ __launch_bounds__(256) void layernorm_to_bf16(
    const float* __restrict__ x, const float* __restrict__ g,
    const float* __restrict__ b, bf16* __restrict__ out) {
  const int row = blockIdx.x;
  const float4 v = ((const float4*)(x + (size_t)row * kDM))[threadIdx.x];
  float s  = v.x + v.y + v.z + v.w;
  float s2 = v.x * v.x + v.y * v.y + v.z * v.z + v.w * v.w;
#pragma unroll
  for (int off = 1; off < 64; off <<= 1) {
    s  += __shfl_xor(s, off);
    s2 += __shfl_xor(s2, off);
  }
  __shared__ float ws[4], ws2[4];
  const int wave = threadIdx.x >> 6, lane = threadIdx.x & 63;
  if (lane == 0) { ws[wave] = s; ws2[wave] = s2; }
  __syncthreads();
  s  = ws[0] + ws[1] + ws[2] + ws[3];
  s2 = ws2[0] + ws2[1] + ws2[2] + ws2[3];
  const float mu  = s * (1.f / kDM);
  const float var = s2 * (1.f / kDM) - mu * mu;
  const float r   = rsqrtf(var + 1e-5f);
  const int c = threadIdx.x * 4;
  const float4 gg = ((const float4*)g)[threadIdx.x];
  const float4 bb = ((const float4*)b)[threadIdx.x];
  bf16* o = out + (size_t)row * kDM + c;
  o[0] = (bf16)((v.x - mu) * r * gg.x + bb.x);
  o[1] = (bf16)((v.y - mu) * r * gg.y + bb.y);
  o[2] = (bf16)((v.z - mu) * r * gg.z + bb.z);
  o[3] = (bf16)((v.w - mu) * r * gg.w + bb.w);
}

// ---------------- bf16 MFMA GEMM: C[M][N] = A[M][K] * BT[N][K]^T ------------
// 128x128 tile, 4 waves, BK=32, linear LDS, global_load_lds (m97 structure).
// K arg = per-chunk K length; blockIdx.z selects the K-chunk (split-K).
template <int MODE>
__global__ __launch_bounds__(256, 2) void gemm_bt(
    const bf16* __restrict__ A, int lda,
    const bf16* __restrict__ BT, int ldbt, int K,
    float* __restrict__ C0, bf16* __restrict__ C1,
    const float* __restrict__ bias, const float* __restrict__ res) {
  __shared__ __align__(16) bf16 As[128 * 32];
  __shared__ __align__(16) bf16 Bs[128 * 32];

  const int tid  = threadIdx.x;
  const int wave = tid >> 6;
  const int lane = tid & 63;
  const int m0 = blockIdx.y * 128;
  const int n0 = blockIdx.x * 128;
  const int kz = blockIdx.z * K;                 // split-K offset
  const int wr = wave >> 1, wc = wave & 1;       // 2x2 wave grid, 64x64 each
  const int lr = lane & 15, kg = lane >> 4;

  const int srow = lane >> 2;                    // staging row within chunk
  const int scol = (lane & 3) * 8;               // staging col (bf16 elems)

  const bf16* Ag0 = A  + (size_t)(m0 + wave * 32 + srow) * lda  + scol + kz;
  const bf16* Ag1 = Ag0 + (size_t)16 * lda;
  const bf16* Bg0 = BT + (size_t)(n0 + wave * 32 + srow) * ldbt + scol + kz;
  const bf16* Bg1 = Bg0 + (size_t)16 * ldbt;
  bf16* Al0 = As + wave * 1024;  // wave stages rows [32w, 32w+32)
  bf16* Al1 = Al0 + 512;
  bf16* Bl0 = Bs + wave * 1024;
  bf16* Bl1 = Bl0 + 512;

  f32x4 acc[4][4] = {};

  for (int kt = 0; kt < K; kt += 32) {
    __syncthreads();                              // protect LDS from prev reads
    gload16(Ag0 + kt, Al0);
    gload16(Ag1 + kt, Al1);
    gload16(Bg0 + kt, Bl0);
    gload16(Bg1 + kt, Bl1);
    __syncthreads();                              // compiler drains vmcnt here

    bf16x8 af[4], bfr[4];
#pragma unroll
    for (int i = 0; i < 4; ++i) {
      af[i]  = *(const bf16x8*)(As + (wr * 64 + i * 16 + lr) * 32 + kg * 8);
      bfr[i] = *(const bf16x8*)(Bs + (wc * 64 + i * 16 + lr) * 32 + kg * 8);
    }
#pragma unroll
    for (int i = 0; i < 4; ++i)
#pragma unroll
      for (int j = 0; j < 4; ++j)
        acc[i][j] =
            __builtin_amdgcn_mfma_f32_16x16x32_bf16(af[i], bfr[j], acc[i][j], 0, 0, 0);
  }

  // epilogue: C/D layout col=lane&15, row=(lane>>4)*4+e  [verified m89]
#pragma unroll
  for (int i = 0; i < 4; ++i) {
    const int mbase = m0 + wr * 64 + i * 16 + kg * 4;
#pragma unroll
    for (int j = 0; j < 4; ++j) {
      const int n = n0 + wc * 64 + j * 16 + lr;
#pragma unroll
      for (int e = 0; e < 4; ++e) {
        const int m = mbase + e;
        const float v = acc[i][j][e];
        if constexpr (MODE == 0) {        // xz: cols<2048 raw xc, else silu(z)
          if (n < kDI) C0[(size_t)m * kDI + n] = v;
          else         C1[(size_t)m * kDI + (n - kDI)] = (bf16)(v / (1.f + expf(-v)));
        } else if constexpr (MODE == 2) { // dt = softplus(v + b_dt)
          const float t = v + bias[n];
          const float sp = (t > 0.f) ? (t + log1pf(expf(-t))) : log1pf(expf(t));
          C0[(size_t)m * kDI + n] = sp;
        } else if constexpr (MODE == 4) { // p = v + b_ff1 (bf16)
          C1[(size_t)m * 8192 + n] = (bf16)(v + bias[n]);
        } else if constexpr (MODE == 6) { // split-K partial, N=1024
          C0[((size_t)blockIdx.z * kM + m) * 1024 + n] = v;
        } else {                          // MODE 7: split-K partial, N=128
          C0[((size_t)blockIdx.z * kM + m) * 128 + n] = v;
        }
      }
    }
  }
}

// ---------------- split-K reduce kernels ----------------
__global__ __launch_bounds__(256) void reduce_dbc(     // SK=8, N=128
    const float* __restrict__ P, float* __restrict__ dbc, bf16* __restrict__ dtlo) {
  const int i = blockIdx.x * 256 + threadIdx.x;        // over kM*128
  float s = 0.f;
#pragma unroll
  for (int z = 0; z < 8; ++z) s += P[(size_t)z * (kM * 128) + i];
  dbc[i] = s;
  const int n = i & 127;
  if (n < 64) dtlo[(size_t)(i >> 7) * 64 + n] = (bf16)s;
}

__global__ __launch_bounds__(256) void reduce_wout(    // SK=2: out1 = x + sum
    const float* __restrict__ P, const float* __restrict__ x,
    float* __restrict__ o) {
  const size_t i = ((size_t)blockIdx.x * 256 + threadIdx.x) * 4;  // kM*1024
  const float4 a  = *(const float4*)&x[i];
  const float4 p0 = *(const float4*)&P[i];
  const float4 p1 = *(const float4*)&P[(size_t)kM * 1024 + i];
  float4 r;
  r.x = a.x + p0.x + p1.x;  r.y = a.y + p0.y + p1.y;
  r.z = a.z + p0.z + p1.z;  r.w = a.w + p0.w + p1.w;
  *(float4*)&o[i] = r;
}

__global__ __launch_bounds__(256) void reduce_ff2(     // SK=4: out=o1+bias+sum
    const float* __restrict__ P, const float* __restrict__ o1,
    const float* __restrict__ bias, float* __restrict__ o) {
  const size_t i = ((size_t)blockIdx.x * 256 + threadIdx.x) * 4;  // kM*1024
  const int n = (int)(i & 1023);
  const float4 a  = *(const float4*)&o1[i];
  const float4 bb = *(const float4*)&bias[n];
  float4 s;
  s.x = a.x + bb.x;  s.y = a.y + bb.y;  s.z = a.z + bb.z;  s.w = a.w + bb.w;
#pragma unroll
  for (int z = 0; z < 4; ++z) {
    const float4 p = *(const float4*)&P[(size_t)z * (kM * 1024) + i];
    s.x += p.x;  s.y += p.y;  s.z += p.z;  s.w += p.w;
  }
  *(float4*)&o[i] = s;
}

// ---------------- depthwise causal conv (D_CONV=4) + silu ----------------
__global__ __launch_bounds__(256) void conv_silu(
    const float* __restrict__ xc_raw, const float* __restrict__ cw,
    const float* __restrict__ cb, float* __restrict__ xf, bf16* __restrict__ xb) {
  const int idx = blockIdx.x * 256 + threadIdx.x;  // over M*DI
  const int d = idx & (kDI - 1);
  const int m = idx >> 11;
  const int l = m & (kL - 1);
  float acc = cb[d];
  const float w0 = cw[d * 4 + 0], w1 = cw[d * 4 + 1], w2 = cw[d * 4 + 2],
              w3 = cw[d * 4 + 3];
  if (l >= 3) acc += xc_raw[(size_t)(m - 3) * kDI + d] * w0;
  if (l >= 2) acc += xc_raw[(size_t)(m - 2) * kDI + d] * w1;
  if (l >= 1) acc += xc_raw[(size_t)(m - 1) * kDI + d] * w2;
  acc += xc_raw[(size_t)m * kDI + d] * w3;
  const float a = acc / (1.f + expf(-acc));        // silu
  xf[idx] = a;
  xb[idx] = (bf16)a;
}

// ---------------- chunked selective scan (one thread per b,d,chunk) --------
__global__ __launch_bounds__(256) void scan_p1(
    const float* __restrict__ dt, const float* __restrict__ xc,
    const float* __restrict__ dbc, const float* __restrict__ a_log,
    float* __restrict__ P, float* __restrict__ Q) {
  const int dg = blockIdx.x & 7;                 // d-group (256 channels)
  const int c  = (blockIdx.x >> 3) & (kNC - 1);
  const int b  = blockIdx.x >> 9;
  const int d  = dg * 256 + threadIdx.x;
  __shared__ __align__(16) float BC[kCH][32];    // cols 0-15 = B, 16-31 = C
  {
    const int l  = threadIdx.x >> 3;             // 32 rows x 8 groups
    const int cg = (threadIdx.x & 7) * 4;
    *(float4*)&BC[l][cg] =
        *(const float4*)&dbc[(size_t)(b * kL + c * kCH + l) * 128 + 64 + cg];
  }
  __syncthreads();
  float A[16];
#pragma unroll
  for (int q = 0; q < 4; ++q) {
    const float4 al = *(const float4*)&a_log[d * 16 + q * 4];
    A[q * 4 + 0] = -__expf(al.x);
    A[q * 4 + 1] = -__expf(al.y);
    A[q * 4 + 2] = -__expf(al.z);
    A[q * 4 + 3] = -__expf(al.w);
  }
  float h[16] = {};
  float sdt = 0.f;
  const size_t rb = ((size_t)b * kL + c * kCH) * kDI + d;
#pragma unroll 2
  for (int l = 0; l < kCH; ++l) {
    const float dtv = dt[rb + (size_t)l * kDI];
    const float xv  = xc[rb + (size_t)l * kDI];
    const float u   = dtv * xv;
    sdt += dtv;
    float Bv[16];
    *(float4*)&Bv[0]  = *(const float4*)&BC[l][0];
    *(float4*)&Bv[4]  = *(const float4*)&BC[l][4];
    *(float4*)&Bv[8]  = *(const float4*)&BC[l][8];
    *(float4*)&Bv[12] = *(const float4*)&BC[l][12];
#pragma unroll
    for (int n = 0; n < 16; ++n) {
      const float dA = __expf(dtv * A[n]);
      h[n] = h[n] * dA + u * Bv[n];
    }
  }
  const size_t o = (((size_t)b * kNC + c) * kDI + d) * 16;
  float Pv[16];
#pragma unroll
  for (int n = 0; n < 16; ++n) Pv[n] = __expf(sdt * A[n]);
#pragma unroll
  for (int q = 0; q < 4; ++q) {
    *(float4*)&P[o + q * 4] = *(float4*)&Pv[q * 4];
    *(float4*)&Q[o + q * 4] = *(float4*)&h[q * 4];
  }
}

__global__ __launch_bounds__(256) void scan_p2(
    const float* __restrict__ P, const float* __restrict__ Q,
    float* __restrict__ H0) {
  const int i  = blockIdx.x * 256 + threadIdx.x;   // over B*DI*16 = 65536
  const int dn = i & (kDI * 16 - 1);
  const int b  = i >> 15;
  float h = 0.f;
#pragma unroll 8
  for (int c = 0; c < kNC; ++c) {
    const size_t idx = ((size_t)(b * kNC + c)) * (kDI * 16) + dn;
    H0[idx] = h;                        // state at START of chunk c
    h = P[idx] * h + Q[idx];
  }
}

__global__ __launch_bounds__(256) void scan_p3(
    const float* __restrict__ dt, const float* __restrict__ xc,
    const float* __restrict__ dbc, const float* __restrict__ a_log,
    const float* __restrict__ d_skip, const bf16* __restrict__ zs,
    const float* __restrict__ H0, bf16* __restrict__ y) {
  const int dg = blockIdx.x & 7;
  const int c  = (blockIdx.x >> 3) & (kNC - 1);
  const int b  = blockIdx.x >> 9;
  const int d  = dg * 256 + threadIdx.x;
  __shared__ __align__(16) float BC[kCH][32];
  {
    const int l  = threadIdx.x >> 3;
    const int cg = (threadIdx.x & 7) * 4;
    *(float4*)&BC[l][cg] =
        *(const float4*)&dbc[(size_t)(b * kL + c * kCH + l) * 128 + 64 + cg];
  }
  __syncthreads();
  float A[16];
#pragma unroll
  for (int q = 0; q < 4; ++q) {
    const float4 al = *(const float4*)&a_log[d * 16 + q * 4];
    A[q * 4 + 0] = -__expf(al.x);
    A[q * 4 + 1] = -__expf(al.y);
    A[q * 4 + 2] = -__expf(al.z);
    A[q * 4 + 3] = -__expf(al.w);
  }
  const float dsk = d_skip[d];
  float h[16];
  const size_t o = (((size_t)b * kNC + c) * kDI + d) * 16;
#pragma unroll
  for (int q = 0; q < 4; ++q)
    *(float4*)&h[q * 4] = *(const float4*)&H0[o + q * 4];
  const size_t rb = ((size_t)b * kL + c * kCH) * kDI + d;
#pragma unroll 2
  for (int l = 0; l < kCH; ++l) {
    const size_t r  = rb + (size_t)l * kDI;
    const float dtv = dt[r];
    const float xv  = xc[r];
    const float zv  = (float)zs[r];
    const float u   = dtv * xv;
    float Bv[16], Cv[16];
    *(float4*)&Bv[0]  = *(const float4*)&BC[l][0];
    *(float4*)&Bv[4]  = *(const float4*)&BC[l][4];
    *(float4*)&Bv[8]  = *(const float4*)&BC[l][8];
    *(float4*)&Bv[12] = *(const float4*)&BC[l][12];
    *(float4*)&Cv[0]  = *(const float4*)&BC[l][16];
    *(float4*)&Cv[4]  = *(const float4*)&BC[l][20];
    *(float4*)&Cv[8]  = *(const float4*)&BC[l][24];
    *(float4*)&Cv[12] = *(const float4*)&BC[l][28];
    float pp[4] = {0.f, 0.f, 0.f, 0.f};
#pragma unroll
    for (int n = 0; n < 16; ++n) {
      const float dA = __expf(dtv * A[n]);
      h[n] = h[n] * dA + u * Bv[n];
      pp[n & 3] += h[n] * Cv[n];
    }
    const float part = (pp[0] + pp[1]) + (pp[2] + pp[3]);
    y[r] = (bf16)((part + dsk * xv) * zv);
  }
}

// ---------------- geglu: v = a * gelu_tanh(g) ----------------
__global__ __launch_bounds__(256) void geglu(
    const bf16* __restrict__ p, bf16* __restrict__ v) {
  const int idx = blockIdx.x * 256 + threadIdx.x;  // over M*4096
  const int m = idx >> 12, n = idx & 4095;
  const float a = (float)p[(size_t)m * 8192 + n];
  const float g = (float)p[(size_t)m * 8192 + 4096 + n];
  const float g3 = g * g * g;
  const float t  = tanhf(0.7978845608028654f * (g + 0.044715f * g3));
  v[idx] = (bf16)(a * (0.5f * g * (1.f + t)));
}

// ---------------- launch ----------------
extern "C" void kernel_launch(void* const* d_in, const int* in_sizes, int n_in,
                              void* d_out, int out_size, void* d_ws, size_t ws_size,
                              hipStream_t stream) {
  const float* x      = (const float*)d_in[0];
  const float* ln1_g  = (const float*)d_in[1];
  const float* ln1_b  = (const float*)d_in[2];
  const float* w_in   = (const float*)d_in[3];
  const float* conv_w = (const float*)d_in[4];
  const float* conv_b = (const float*)d_in[5];
  const float* w_x    = (const float*)d_in[6];
  const float* w_dt   = (const float*)d_in[7];
  const float* b_dt   = (const float*)d_in[8];
  const float* a_log  = (const float*)d_in[9];
  const float* d_skip = (const float*)d_in[10];
  const float* w_out  = (const float*)d_in[11];
  const float* ln2_g  = (const float*)d_in[12];
  const float* ln2_b  = (const float*)d_in[13];
  const float* w_ff1  = (const float*)d_in[14];
  const float* b_ff1  = (const float*)d_in[15];
  const float* w_ff2  = (const float*)d_in[16];
  const float* b_ff2  = (const float*)d_in[17];
  float* out = (float*)d_out;
  char* ws = (char*)d_ws;

  // arena layout (bytes); lifetimes allow the noted aliasing
  bf16* wT_in  = (bf16*)(ws + 0);          //  8 MiB [4096][1024]
  bf16* wT_x   = (bf16*)(ws + 8388608);    //  0.5 MiB [128][2048] (pad 96->128)
  bf16* wT_dt  = (bf16*)(ws + 8912896);    //  0.25 MiB [2048][64]
  bf16* wT_out = (bf16*)(ws + 9175040);    //  4 MiB [1024][2048]
  bf16* wT_ff1 = (bf16*)(ws + 13369344);   // 16 MiB [8192][1024]
  bf16* wT_ff2 = (bf16*)(ws + 30146560);   //  8 MiB [1024][4096]
  bf16* h_bf   = (bf16*)(ws + 38535168);   //  8 MiB (h, later h2)
  float* xcraw = (float*)(ws + 46923776);  // 32 MiB (xc_raw -> dt -> v_bf16)
  bf16* zs     = (bf16*)(ws + 80478208);   // 16 MiB (silu(z) -> out1 f32)
  float* xcf   = (float*)(ws + 97255424);  // 32 MiB xc post-silu f32
  bf16* xcb    = (bf16*)(ws + 130809856);  // 16 MiB (xc bf16 -> y bf16)
  float* dbc   = (float*)(ws + 147587072); //  2 MiB [4096][128]
  bf16* dtlo   = (bf16*)(ws + 149684224);  //  0.5 MiB [4096][64]
  bf16* pbuf   = (bf16*)(ws + 150208512);  // 64 MiB [4096][8192]
  // aliases
  float* dtbuf = xcraw;
  bf16*  vbuf  = (bf16*)xcraw;
  float* out1  = (float*)zs;
  bf16*  ybuf  = xcb;
  bf16*  h2    = h_bf;
  // pbuf region reuse (sequential lifetimes):
  //   dbc split-K partials (8x2MiB) -> P/Q/H0 (3x16MiB) -> w_out partials
  //   (2x16MiB) -> p (ff1 out, 64MiB) -> ff2 partials (4x16MiB)
  float* Part  = (float*)pbuf;
  float* Pbuf  = (float*)pbuf;
  float* Qbuf  = (float*)((char*)pbuf + (16 << 20));
  float* H0buf = (float*)((char*)pbuf + (32 << 20));

  const dim3 tb(256);
  // weight transposes (fp32 -> bf16 [N][K])
  transpose_to_bf16<<<dim3(32, 128), tb, 0, stream>>>(w_in, wT_in, 1024, 4096, 4096);
  transpose_to_bf16<<<dim3(64, 4), tb, 0, stream>>>(w_x, wT_x, 2048, 96, 128);
  transpose_to_bf16<<<dim3(2, 64), tb, 0, stream>>>(w_dt, wT_dt, 64, 2048, 2048);
  transpose_to_bf16<<<dim3(64, 32), tb, 0, stream>>>(w_out, wT_out, 2048, 1024, 1024);
  transpose_to_bf16<<<dim3(32, 256), tb, 0, stream>>>(w_ff1, wT_ff1, 1024, 8192, 8192);
  transpose_to_bf16<<<dim3(128, 32), tb, 0, stream>>>(w_ff2, wT_ff2, 4096, 1024, 1024);

  layernorm_to_bf16<<<kM, tb, 0, stream>>>(x, ln1_g, ln1_b, h_bf);

  // xz = h @ w_in : xc_raw fp32 + silu(z) bf16
  gemm_bt<0><<<dim3(32, 32), tb, 0, stream>>>(h_bf, 1024, wT_in, 1024, 1024,
                                              xcraw, zs, nullptr, nullptr);
  conv_silu<<<(kM * kDI) / 256, tb, 0, stream>>>(xcraw, conv_w, conv_b, xcf, xcb);

  // dbc = xc @ w_x (N padded to 128): split-K SK=8 (was 32 blocks total)
  gemm_bt<7><<<dim3(1, 32, 8), tb, 0, stream>>>(xcb, 2048, wT_x, 2048, 256,
                                                Part, nullptr, nullptr, nullptr);
  reduce_dbc<<<(kM * 128) / 256, tb, 0, stream>>>(Part, dbc, dtlo);

  // dt = softplus(dt_lo @ w_dt + b_dt)
  gemm_bt<2><<<dim3(16, 32), tb, 0, stream>>>(dtlo, 64, wT_dt, 64, 64,
                                              dtbuf, nullptr, b_dt, nullptr);

  // chunked scan: p1 (chunk summaries) -> p2 (combine) -> p3 (emit y)
  scan_p1<<<kB * kNC * (kDI / 256), tb, 0, stream>>>(dtbuf, xcf, dbc, a_log,
                                                     Pbuf, Qbuf);
  scan_p2<<<(kB * kDI * 16) / 256, tb, 0, stream>>>(Pbuf, Qbuf, H0buf);
  scan_p3<<<kB * kNC * (kDI / 256), tb, 0, stream>>>(dtbuf, xcf, dbc, a_log,
                                                     d_skip, zs, H0buf, ybuf);

  // out1 = x + y @ w_out : split-K SK=2
  gemm_bt<6><<<dim3(8, 32, 2), tb, 0, stream>>>(ybuf, 2048, wT_out, 2048, 1024,
                                                Part, nullptr, nullptr, nullptr);
  reduce_wout<<<(kM * 1024) / 1024, tb, 0, stream>>>(Part, x, out1);

  layernorm_to_bf16<<<kM, tb, 0, stream>>>(out1, ln2_g, ln2_b, h2);

  // p = h2 @ w_ff1 + b_ff1
  gemm_bt<4><<<dim3(64, 32), tb, 0, stream>>>(h2, 1024, wT_ff1, 1024, 1024,
                                              nullptr, pbuf, b_ff1, nullptr);
  geglu<<<(kM * 4096) / 256, tb, 0, stream>>>(pbuf, vbuf);

  // d_out = out1 + v @ w_ff2 + b_ff2 : split-K SK=4
  gemm_bt<6><<<dim3(8, 32, 4), tb, 0, stream>>>(vbuf, 4096, wT_ff2, 4096, 1024,
                                                Part, nullptr, nullptr, nullptr);
  reduce_ff2<<<(kM * 1024) / 1024, tb, 0, stream>>>(Part, out1, b_ff2, out);
  (void)in_sizes; (void)n_in; (void)out_size; (void)ws_size;
}